// Round 13
// baseline (849.147 us; speedup 1.0000x reference)
//
#include <hip/hip_runtime.h>
#include <cstdint>
#include <cstddef>

#define NN 20000
#define NE 320000
#define NG 256
#define NB 79   // ceil(NN/256)

typedef unsigned short u16;
typedef __attribute__((ext_vector_type(8))) short bf16x8;
typedef __attribute__((ext_vector_type(4))) float f32x4;
typedef __attribute__((ext_vector_type(4))) unsigned u32x4;

// ---------------- bf16 helpers (storage bf16, math fp32) ----------------
__device__ inline float b2f(u16 h){
  union { unsigned u; float f; } v; v.u = ((unsigned)h) << 16; return v.f;
}
__device__ inline u16 f2b(float f){
  union { float f; unsigned u; } v; v.f = f;
  unsigned r = v.u + 0x7FFFu + ((v.u >> 16) & 1u);   // round-nearest-even
  return (u16)(r >> 16);
}
__device__ inline void up8(const uint4& v, float* a){
  union { unsigned u; float f; } t;
  t.u = v.x << 16;         a[0] = t.f;
  t.u = v.x & 0xffff0000u; a[1] = t.f;
  t.u = v.y << 16;         a[2] = t.f;
  t.u = v.y & 0xffff0000u; a[3] = t.f;
  t.u = v.z << 16;         a[4] = t.f;
  t.u = v.z & 0xffff0000u; a[5] = t.f;
  t.u = v.w << 16;         a[6] = t.f;
  t.u = v.w & 0xffff0000u; a[7] = t.f;
}
__device__ inline unsigned pk2(float a, float b){
  return (unsigned)f2b(a) | (((unsigned)f2b(b)) << 16);
}
__device__ inline void bnrelu8(float* b, const float* sc, const float* sh){
  #pragma unroll
  for (int k = 0; k < 8; k++) b[k] = fmaxf(fmaf(b[k], sc[k], sh[k]), 0.f);
}

__device__ inline void gload_lds16(const void* g, void* l){
  __builtin_amdgcn_global_load_lds(
      (const __attribute__((address_space(1))) unsigned int*)g,
      (__attribute__((address_space(3))) unsigned int*)l, 16, 0, 0);
}

// ---------------- utility kernels ----------------

__global__ void k_zero(int* __restrict__ p, int n){
  int i = blockIdx.x*blockDim.x + threadIdx.x;
  if (i < n) p[i] = 0;
}

__global__ void k_deg(const int* __restrict__ ei, int* __restrict__ deg){
  int e = blockIdx.x*blockDim.x + threadIdx.x;
  if (e < NE) atomicAdd(&deg[ei[NE + e]], 1);   // dst = ei[1][e]
}

// degree histogram -> rank (degree-sorted position per original node)
__global__ void k_hist(const int* __restrict__ deg, int* __restrict__ hist){
  int i = blockIdx.x*blockDim.x + threadIdx.x;
  if (i < NN) atomicAdd(&hist[min(deg[i], 255)], 1);
}
__global__ void k_hscan(const int* __restrict__ hist, int* __restrict__ binoff){
  __shared__ int sm[256];
  int tid = threadIdx.x;
  sm[tid] = hist[tid];
  __syncthreads();
  for (int d = 1; d < 256; d <<= 1){
    int t = (tid >= d) ? sm[tid - d] : 0;
    __syncthreads();
    sm[tid] += t;
    __syncthreads();
  }
  binoff[tid] = sm[tid] - hist[tid];   // exclusive
}
__global__ void k_scat(const int* __restrict__ deg, int* __restrict__ binoff,
                       int* __restrict__ rank){
  int i = blockIdx.x*blockDim.x + threadIdx.x;
  if (i < NN){
    int p = atomicAdd(&binoff[min(deg[i], 255)], 1);
    rank[i] = p;
  }
}
// deg2[rank[i]] = deg[i]
__global__ void k_sdeg(const int* __restrict__ deg, const int* __restrict__ rank,
                       int* __restrict__ deg2){
  int i = blockIdx.x*blockDim.x + threadIdx.x;
  if (i < NN) deg2[rank[i]] = deg[i];
}

// two-level scan: counts[NN] -> offs[NN+1]; also emits dinv
__global__ void k_scan1(const int* __restrict__ counts, int* __restrict__ bsum,
                        float* __restrict__ dinv){
  __shared__ int sm[256];
  int b = blockIdx.x, tid = threadIdx.x, idx = b*256 + tid;
  int v = (idx < NN) ? counts[idx] : 0;
  if (idx < NN) dinv[idx] = rsqrtf(1.0f + (float)v);
  sm[tid] = v;
  __syncthreads();
  for (int d = 128; d > 0; d >>= 1){
    if (tid < d) sm[tid] += sm[tid + d];
    __syncthreads();
  }
  if (tid == 0) bsum[b] = sm[0];
}
__global__ void k_scan2(int* __restrict__ bsum){
  if (threadIdx.x == 0){
    int c = 0;
    for (int i = 0; i < NB; i++){ int t = bsum[i]; bsum[i] = c; c += t; }
    bsum[NB] = c;
  }
}
__global__ void k_scan3(const int* __restrict__ counts, const int* __restrict__ bsum,
                        int* __restrict__ offs){
  __shared__ int sm[256];
  int b = blockIdx.x, tid = threadIdx.x, idx = b*256 + tid;
  int v = (idx < NN) ? counts[idx] : 0;
  sm[tid] = v;
  __syncthreads();
  for (int d = 1; d < 256; d <<= 1){
    int t = (tid >= d) ? sm[tid - d] : 0;
    __syncthreads();
    sm[tid] += t;
    __syncthreads();
  }
  if (idx < NN) offs[idx] = bsum[b] + sm[tid] - v;
  if (idx == NN - 1) offs[NN] = bsum[NB];
}

// CSR fill directly in sorted space
__global__ void k_fill2(const int* __restrict__ ei, const int* __restrict__ offs2,
                        const int* __restrict__ rank, int* __restrict__ cur,
                        int* __restrict__ srcs2){
  int e = blockIdx.x*blockDim.x + threadIdx.x;
  if (e < NE){
    int s = ei[e];
    int dd = rank[ei[NE + e]];
    int p = atomicAdd(&cur[dd], 1);
    srcs2[offs2[dd] + p] = rank[s];
  }
}

__global__ void k_bounds(const int* __restrict__ batch, int* __restrict__ start){
  int i = blockIdx.x*blockDim.x + threadIdx.x;
  if (i < NN){
    int b  = batch[i];
    int bp = (i == 0) ? -1 : batch[i-1];
    for (int g = bp + 1; g <= b; g++) start[g] = i;
    if (i == NN - 1){
      for (int g = b + 1; g <= NG; g++) start[g] = NN;
    }
  }
}

// cast fp32 x -> bf16, permuted into sorted row order
__global__ void k_cast_p(const float4* __restrict__ x, const int* __restrict__ rank,
                         ushort4* __restrict__ xb){
  int t = blockIdx.x*blockDim.x + threadIdx.x;
  if (t >= NN*32) return;
  int i = t >> 5, c = t & 31;
  float4 v = x[t];
  ushort4 o; o.x = f2b(v.x); o.y = f2b(v.y); o.z = f2b(v.z); o.w = f2b(v.w);
  xb[(size_t)rank[i]*32 + c] = o;
}

// merged weight prep: 7 weights, fp32 [K,N] -> bf16 [N,K]
struct WPArgs {
  const float* w[7];
  u16* wt[7];
  int K[7], N[7];
  int tstart[8];   // tile prefix
};
__global__ __launch_bounds__(256) void k_wprep7(WPArgs a){
  __shared__ float sm[64][65];
  int bid = blockIdx.x;
  int wi = 0;
  while (wi < 6 && bid >= a.tstart[wi+1]) wi++;
  int tt = bid - a.tstart[wi];
  int K = a.K[wi], N = a.N[wi];
  int nk = K >> 6;
  int kb = (tt % nk) * 64, nb = (tt / nk) * 64;
  const float* w = a.w[wi];
  u16* wt = a.wt[wi];
  int tid = threadIdx.x;
  #pragma unroll
  for (int i = 0; i < 16; i++){
    int t = i*256 + tid;
    int r = t >> 6, c = t & 63;
    sm[r][c] = w[(size_t)(kb + r) * N + nb + c];
  }
  __syncthreads();
  #pragma unroll
  for (int i = 0; i < 16; i++){
    int t = i*256 + tid;
    int r = t >> 6, c = t & 63;
    wt[(size_t)(nb + r) * K + kb + c] = f2b(sm[c][r]);
  }
}

// ---------------- aggregation (bf16 in/out, fp32 accumulate) ----------------
// Sorted-row layout (degree-uniform waves) + XCD channel grouping
// (group = blockIdx%8 -> same XCD L2 slice) + nontemporal output stores.
template<int GR, bool BN>
__global__ void k_agg_s(const uint4* __restrict__ in, uint4* __restrict__ out,
                        const float* __restrict__ dinv, const int* __restrict__ offs,
                        const int* __restrict__ srcs,
                        const float* __restrict__ sumv, const float* __restrict__ sqv,
                        const float* __restrict__ gam,  const float* __restrict__ bet){
  constexpr int C8 = GR * 8;
  int group = blockIdx.x & 7;
  int tile  = blockIdx.x >> 3;
  int flat  = tile*256 + threadIdx.x;
  if (flat >= NN * GR) return;
  int i  = flat / GR;             // sorted node index
  int cg = flat - i * GR;
  int c  = group * GR + cg;       // uint4 index within row
  float sc[8], sh[8];
  if (BN){
    #pragma unroll
    for (int k = 0; k < 8; k++){
      int ch = c*8 + k;
      float m  = sumv[ch] * (1.0f / NN);
      float vv = sqv[ch] * (1.0f / NN) - m * m;
      float rs = rsqrtf(vv + 1e-5f);
      sc[k] = gam[ch] * rs;
      sh[k] = bet[ch] - m * sc[k];
    }
  }
  float di = dinv[i];
  float a[8], acc[8];
  up8(in[(size_t)i * C8 + c], a);
  if (BN) bnrelu8(a, sc, sh);
  #pragma unroll
  for (int k = 0; k < 8; k++) acc[k] = a[k] * di;

  int e = offs[i], e1 = offs[i + 1];
  for (; e + 4 <= e1; e += 4){
    int sA = srcs[e], sB = srcs[e+1], sC = srcs[e+2], sD = srcs[e+3];
    float dA = dinv[sA], dB = dinv[sB], dC = dinv[sC], dD = dinv[sD];
    uint4 yA = in[(size_t)sA * C8 + c];
    uint4 yB = in[(size_t)sB * C8 + c];
    uint4 yC = in[(size_t)sC * C8 + c];
    uint4 yD = in[(size_t)sD * C8 + c];
    float b[8];
    up8(yA, b);
    if (BN) bnrelu8(b, sc, sh);
    #pragma unroll
    for (int k = 0; k < 8; k++) acc[k] = fmaf(b[k], dA, acc[k]);
    up8(yB, b);
    if (BN) bnrelu8(b, sc, sh);
    #pragma unroll
    for (int k = 0; k < 8; k++) acc[k] = fmaf(b[k], dB, acc[k]);
    up8(yC, b);
    if (BN) bnrelu8(b, sc, sh);
    #pragma unroll
    for (int k = 0; k < 8; k++) acc[k] = fmaf(b[k], dC, acc[k]);
    up8(yD, b);
    if (BN) bnrelu8(b, sc, sh);
    #pragma unroll
    for (int k = 0; k < 8; k++) acc[k] = fmaf(b[k], dD, acc[k]);
  }
  for (; e < e1; e++){
    int s = srcs[e];
    float ds = dinv[s];
    float b[8];
    up8(in[(size_t)s * C8 + c], b);
    if (BN) bnrelu8(b, sc, sh);
    #pragma unroll
    for (int k = 0; k < 8; k++) acc[k] = fmaf(b[k], ds, acc[k]);
  }
  #pragma unroll
  for (int k = 0; k < 8; k++) acc[k] *= di;
  u32x4 o;
  o.x = pk2(acc[0], acc[1]); o.y = pk2(acc[2], acc[3]);
  o.z = pk2(acc[4], acc[5]); o.w = pk2(acc[6], acc[7]);
  __builtin_nontemporal_store(o, (u32x4*)&out[(size_t)i * C8 + c]);
}

// ---------------- MFMA GEMM: A bf16 [M,K], BT bf16 [N,K], C bf16 [M,N] ----------------
// MODE: 0=bias, 1=bias+relu, 3=bias + relu(BN(C_old)) add (BN from raw stats p0..p3)
// STATS: accumulate per-column sum/sumsq of (acc+bias) into p0/p1
template<int MODE, bool STATS>
__global__ __launch_bounds__(256, 4) void k_mfma(const u16* __restrict__ A,
                                                 const u16* __restrict__ BT,
                                                 const float* __restrict__ bias,
                                                 u16* __restrict__ C,
                                                 float* __restrict__ p0,
                                                 float* __restrict__ p1,
                                                 const float* __restrict__ p2,
                                                 const float* __restrict__ p3,
                                                 int M, int K, int Nc){
  __shared__ u16 S[128*128];          // staging: As = S[0:8192), Bs = S[8192:16384)
  u16* As = S;
  u16* Bs = S + 128*64;
  const int tid = threadIdx.x;
  const int lane = tid & 63;
  const int quad = lane >> 4;
  const int l16 = lane & 15;
  const int wid = tid >> 6;
  const int wm = wid & 1, wn = wid >> 1;
  const int bm = blockIdx.x * 128, bn = blockIdx.y * 128;

  f32x4 acc[4][4];
  #pragma unroll
  for (int i = 0; i < 4; i++)
    #pragma unroll
    for (int j = 0; j < 4; j++)
      acc[i][j] = (f32x4){0.f, 0.f, 0.f, 0.f};

  const int srow = tid >> 3;
  const int scol8 = tid & 7;
  for (int k0 = 0; k0 < K; k0 += 64){
    #pragma unroll
    for (int i = 0; i < 4; i++){
      int row = i*32 + srow;
      int gc = (scol8 ^ (row & 7)) * 8;
      int lofs = row*64 + scol8*8;
      gload_lds16(A + (size_t)(bm + row) * K + k0 + gc, As + lofs);
      gload_lds16(BT + (size_t)(bn + row) * K + k0 + gc, Bs + lofs);
    }
    __syncthreads();
    #pragma unroll
    for (int kk = 0; kk < 2; kk++){
      const int col8 = kk*4 + quad;
      bf16x8 af[4], bfr[4];
      #pragma unroll
      for (int mi = 0; mi < 4; mi++){
        int row = wm*64 + mi*16 + l16;
        af[mi] = *(const bf16x8*)(As + row*64 + ((col8 ^ (row & 7)) * 8));
      }
      #pragma unroll
      for (int ni = 0; ni < 4; ni++){
        int row = wn*64 + ni*16 + l16;
        bfr[ni] = *(const bf16x8*)(Bs + row*64 + ((col8 ^ (row & 7)) * 8));
      }
      #pragma unroll
      for (int mi = 0; mi < 4; mi++)
        #pragma unroll
        for (int ni = 0; ni < 4; ni++)
          acc[mi][ni] = __builtin_amdgcn_mfma_f32_16x16x32_bf16(af[mi], bfr[ni], acc[mi][ni], 0, 0, 0);
    }
    __syncthreads();
  }
  // register epilogue: bias (+stats, +relu), round to bf16 into LDS [row][col]
  #pragma unroll
  for (int ni = 0; ni < 4; ni++){
    int colL = wn*64 + ni*16 + l16;
    float bb = bias[bn + colL];
    float s = 0.f, s2 = 0.f;
    #pragma unroll
    for (int mi = 0; mi < 4; mi++){
      int rbase = wm*64 + mi*16 + quad*4;
      #pragma unroll
      for (int r = 0; r < 4; r++){
        int rowL = rbase + r;
        float v = acc[mi][ni][r] + bb;
        if (STATS && (bm + rowL) < M){ s += v; s2 += v * v; }
        if (MODE == 1) v = fmaxf(v, 0.f);
        S[rowL*128 + colL] = f2b(v);
      }
    }
    if (STATS){
      s  += __shfl_xor(s, 16, 64);  s  += __shfl_xor(s, 32, 64);
      s2 += __shfl_xor(s2, 16, 64); s2 += __shfl_xor(s2, 32, 64);
      if (quad == 0){
        atomicAdd(&p0[bn + colL], s);
        atomicAdd(&p1[bn + colL], s2);
      }
    }
  }
  __syncthreads();
  // blast: 16B per lane, full-line coalesced stores
  #pragma unroll
  for (int it = 0; it < 8; it++){
    int idx = it*256 + tid;
    int rl = idx >> 4, cq = idx & 15;
    int row = bm + rl;
    if (row < M){
      int col0 = bn + cq*8;
      uint4 w = *(const uint4*)(S + rl*128 + cq*8);
      u16* cp = C + (size_t)row * Nc + col0;
      if (MODE == 3){
        float o[8], ov[8];
        up8(w, o);
        uint4 old = *(const uint4*)cp;
        up8(old, ov);
        #pragma unroll
        for (int k = 0; k < 8; k++){
          int ch = col0 + k;
          float m  = p0[ch] * (1.0f / NN);
          float vv = p1[ch] * (1.0f / NN) - m * m;
          float rs = rsqrtf(vv + 1e-5f);
          float sc = p2[ch] * rs;
          float sh = p3[ch] - m * sc;
          o[k] += fmaxf(fmaf(ov[k], sc, sh), 0.f);
        }
        uint4 ou;
        ou.x = pk2(o[0], o[1]); ou.y = pk2(o[2], o[3]);
        ou.z = pk2(o[4], o[5]); ou.w = pk2(o[6], o[7]);
        *(uint4*)cp = ou;
      } else {
        *(uint4*)cp = w;
      }
    }
  }
}

// ---------------- fp32 GEMM (MLP tail, small M) ----------------
template<bool RELU>
__global__ __launch_bounds__(256) void k_gemm(const float* __restrict__ A,
                                              const float* __restrict__ B,
                                              const float* __restrict__ bias,
                                              float* __restrict__ C,
                                              int M, int K, int Nc){
  __shared__ float As[16][68];
  __shared__ float Bs[16][64];
  const int tid = threadIdx.x;
  const int tx = tid & 15, ty = tid >> 4;
  const int bm = blockIdx.x * 64, bn = blockIdx.y * 64;
  const int arow = tid >> 2, akq = (tid & 3) << 2;
  const int brow = tid >> 4, bcol = (tid & 15) << 2;
  float acc[4][4] = {{0.f}};
  const bool aval = (bm + arow) < M;
  const float* Aptr = A + (size_t)(bm + arow) * K + akq;
  const float* Bptr = B + (size_t)brow * Nc + bn + bcol;
  for (int k0 = 0; k0 < K; k0 += 16){
    float4 av = make_float4(0.f, 0.f, 0.f, 0.f);
    if (aval) av = *(const float4*)(Aptr + k0);
    float4 bv = *(const float4*)(Bptr + (size_t)k0 * Nc);
    As[akq + 0][arow] = av.x;
    As[akq + 1][arow] = av.y;
    As[akq + 2][arow] = av.z;
    As[akq + 3][arow] = av.w;
    *(float4*)&Bs[brow][bcol] = bv;
    __syncthreads();
    #pragma unroll
    for (int kk = 0; kk < 16; kk++){
      const float4 a = *(const float4*)(&As[kk][ty << 2]);
      const float4 b = *(const float4*)(&Bs[kk][tx << 2]);
      const float ar[4] = {a.x, a.y, a.z, a.w};
      const float br[4] = {b.x, b.y, b.z, b.w};
      #pragma unroll
      for (int i = 0; i < 4; i++)
        #pragma unroll
        for (int j = 0; j < 4; j++)
          acc[i][j] = fmaf(ar[i], br[j], acc[i][j]);
    }
    __syncthreads();
  }
  const int col = bn + (tx << 2);
  const float4 bb = *(const float4*)(bias + col);
  #pragma unroll
  for (int i = 0; i < 4; i++){
    int row = bm + (ty << 2) + i;
    if (row < M){
      float4 o;
      o.x = acc[i][0] + bb.x;
      o.y = acc[i][1] + bb.y;
      o.z = acc[i][2] + bb.z;
      o.w = acc[i][3] + bb.w;
      if (RELU){
        o.x = fmaxf(o.x, 0.f); o.y = fmaxf(o.y, 0.f);
        o.z = fmaxf(o.z, 0.f); o.w = fmaxf(o.w, 0.f);
      }
      *(float4*)(C + (size_t)row * Nc + col) = o;
    }
  }
}

// ---------------- mean pool: h2 bf16 [NN,1024] sorted-rows -> pooled fp32 [NG,1024]
__global__ __launch_bounds__(256) void k_pool_b(const u16* __restrict__ h,
                                                const int* __restrict__ start,
                                                const int* __restrict__ rank,
                                                float* __restrict__ pooled){
  __shared__ float sm[128*8];
  int g = blockIdx.x;
  int half = threadIdx.x >> 7;
  int cb = threadIdx.x & 127;
  int c = cb << 3;
  int r0 = start[g], r1 = start[g + 1];
  float acc[8] = {0.f,0.f,0.f,0.f,0.f,0.f,0.f,0.f};
  for (int r = r0 + half; r < r1; r += 2){
    int rr = rank[r];
    float b[8];
    up8(*(const uint4*)(h + (size_t)rr * 1024 + c), b);
    #pragma unroll
    for (int k = 0; k < 8; k++) acc[k] += b[k];
  }
  if (half){
    #pragma unroll
    for (int k = 0; k < 8; k++) sm[cb*8 + k] = acc[k];
  }
  __syncthreads();
  if (!half){
    float inv = (r1 > r0) ? (1.0f / (float)(r1 - r0)) : 0.0f;
    float o[8];
    #pragma unroll
    for (int k = 0; k < 8; k++) o[k] = (acc[k] + sm[cb*8 + k]) * inv;
    float4* dst = (float4*)(pooled + (size_t)g * 1024 + c);
    dst[0] = make_float4(o[0], o[1], o[2], o[3]);
    dst[1] = make_float4(o[4], o[5], o[6], o[7]);
  }
}

// ---------------- host launcher ----------------

extern "C" void kernel_launch(void* const* d_in, const int* in_sizes, int n_in,
                              void* d_out, int out_size, void* d_ws, size_t ws_size,
                              hipStream_t stream) {
  const float* x    = (const float*)d_in[0];
  const int*   ei   = (const int*)d_in[1];
  const int*   bat  = (const int*)d_in[2];
  const float* w0   = (const float*)d_in[3];
  const float* b0   = (const float*)d_in[4];
  const float* a_w1 = (const float*)d_in[5],  *a_b1  = (const float*)d_in[6];
  const float* a_g1 = (const float*)d_in[7],  *a_be1 = (const float*)d_in[8];
  const float* a_w2 = (const float*)d_in[9],  *a_b2  = (const float*)d_in[10];
  const float* a_g2 = (const float*)d_in[11], *a_be2 = (const float*)d_in[12];
  const float* a_w3 = (const float*)d_in[13], *a_b3  = (const float*)d_in[14];
  const float* c_w1 = (const float*)d_in[15], *c_b1  = (const float*)d_in[16];
  const float* c_g1 = (const float*)d_in[17], *c_be1 = (const float*)d_in[18];
  const float* c_w2 = (const float*)d_in[19], *c_b2  = (const float*)d_in[20];
  const float* c_g2 = (const float*)d_in[21], *c_be2 = (const float*)d_in[22];
  const float* c_w3 = (const float*)d_in[23], *c_b3  = (const float*)d_in[24];
  const float* mw1  = (const float*)d_in[25], *mb1   = (const float*)d_in[26];
  const float* mw2  = (const float*)d_in[27], *mb2   = (const float*)d_in[28];
  float* out = (float*)d_out;

  char* pp = (char*)d_ws;
  auto alloc = [&](size_t b)->char*{ char* r = pp; pp += (b + 255) & ~(size_t)255; return r; };

  const size_t CH = (size_t)NN * 2;
  char* R = alloc(2304 * CH);                      // 92.16 MB
  float* dinv = (float*)alloc((size_t)NN * 4);     // sorted space
  int* icomb  = (int*)alloc((size_t)2 * NN * 4);   // deg + cur
  int* deg    = icomb;
  int* cur    = icomb + NN;
  int* deg2   = (int*)alloc((size_t)NN * 4);       // sorted space
  int* rank   = (int*)alloc((size_t)NN * 4);       // orig -> sorted
  int* offs   = (int*)alloc((size_t)(NN + 1) * 4); // sorted space
  int* bsum   = (int*)alloc((size_t)(NB + 1) * 4);
  int* srcs   = (int*)alloc((size_t)NE * 4);       // sorted space
  int* startg = (int*)alloc((size_t)(NG + 1) * 4);
  int* hist   = (int*)alloc(256 * 4);
  int* binoff = (int*)alloc(256 * 4);
  float* SB   = (float*)alloc(5376 * 4);
  float* sA1 = SB;          // 384*2
  float* sA2 = SB + 768;    // 512*2
  float* sC1 = SB + 1792;   // 768*2
  float* sC2 = SB + 3328;   // 1024*2
  u16* WT  = (u16*)alloc(2162688 * 2);             // 4.33 MB
  u16* wt0  = WT;                // 256x128
  u16* wtA1 = WT + 32768;        // 384x256
  u16* wtA2 = WT + 131072;       // 512x384
  u16* wtA3 = WT + 327680;       // 512x256
  u16* wtC1 = WT + 458752;       // 768x512
  u16* wtC2 = WT + 851968;       // 1024x768
  u16* wtC3 = WT + 1638400;      // 1024x512
  float* P  = (float*)WT;        // overlaid with WT (disjoint lifetime)
  float* Hh = P + (size_t)NG * 1024;

  auto slot = [&](int s)->u16*{ return (u16*)(R + (size_t)s * CH); };
  u16* xb  = slot(512);
  u16* ax  = slot(0);
  u16* h0  = slot(128);
  u16* ah0 = slot(1664);
  u16* t1  = slot(1920);
  u16* at  = slot(1280);
  u16* h1  = slot(768);
  u16* ah1 = slot(1792);
  u16* u1  = slot(0);
  u16* au  = slot(1024);
  u16* h2  = slot(0);

  auto cdiv = [](int a, int b){ return (a + b - 1) / b; };

  // graph preprocessing (all tensors in degree-sorted row order)
  k_zero<<<cdiv(2*NN,256),256,0,stream>>>(icomb, 2*NN);
  k_zero<<<cdiv(5376,256),256,0,stream>>>((int*)SB, 5376);
  k_zero<<<1,256,0,stream>>>(hist, 256);
  k_deg <<<cdiv(NE,256),256,0,stream>>>(ei, deg);
  k_hist<<<cdiv(NN,256),256,0,stream>>>(deg, hist);
  k_hscan<<<1,256,0,stream>>>(hist, binoff);
  k_scat<<<cdiv(NN,256),256,0,stream>>>(deg, binoff, rank);
  k_sdeg<<<cdiv(NN,256),256,0,stream>>>(deg, rank, deg2);
  k_scan1<<<NB,256,0,stream>>>(deg2, bsum, dinv);
  k_scan2<<<1,64,0,stream>>>(bsum);
  k_scan3<<<NB,256,0,stream>>>(deg2, bsum, offs);
  k_fill2<<<cdiv(NE,256),256,0,stream>>>(ei, offs, rank, cur, srcs);
  k_bounds<<<cdiv(NN,256),256,0,stream>>>(bat, startg);
  k_cast_p<<<cdiv(NN*32,256),256,0,stream>>>((const float4*)x, rank, (ushort4*)xb);

  // merged weight prep (fp32 [K,N] -> bf16 [N,K], 7 weights, 1 launch)
  {
    WPArgs wa;
    const float* ws[7] = {w0, a_w1, a_w2, a_w3, c_w1, c_w2, c_w3};
    u16* wts[7] = {wt0, wtA1, wtA2, wtA3, wtC1, wtC2, wtC3};
    int Ks[7] = {128, 256, 384, 256, 512, 768, 512};
    int Ns[7] = {256, 384, 512, 512, 768, 1024, 1024};
    int acc = 0;
    for (int i = 0; i < 7; i++){
      wa.w[i] = ws[i]; wa.wt[i] = wts[i]; wa.K[i] = Ks[i]; wa.N[i] = Ns[i];
      wa.tstart[i] = acc;
      acc += (Ks[i]/64) * (Ns[i]/64);
    }
    wa.tstart[7] = acc;
    k_wprep7<<<acc,256,0,stream>>>(wa);
  }

  // agg: sorted + XCD-grouped; plain or fused BN-apply of input from raw stats
  auto agg = [&](const u16* in, u16* o, int C, const float* st,
                 const float* g, const float* be){
    int GR = C / 64;                      // uint4s per group (8 groups)
    int gb = 8 * cdiv(NN * GR, 256);
    if (!st){
      switch (GR){
        case 2: k_agg_s<2,false><<<gb,256,0,stream>>>((const uint4*)in,(uint4*)o,dinv,offs,srcs,nullptr,nullptr,nullptr,nullptr); break;
        case 4: k_agg_s<4,false><<<gb,256,0,stream>>>((const uint4*)in,(uint4*)o,dinv,offs,srcs,nullptr,nullptr,nullptr,nullptr); break;
        case 8: k_agg_s<8,false><<<gb,256,0,stream>>>((const uint4*)in,(uint4*)o,dinv,offs,srcs,nullptr,nullptr,nullptr,nullptr); break;
        default: break;
      }
    } else {
      switch (GR){
        case 6:  k_agg_s<6,true><<<gb,256,0,stream>>>((const uint4*)in,(uint4*)o,dinv,offs,srcs,st,st+C,g,be); break;
        case 12: k_agg_s<12,true><<<gb,256,0,stream>>>((const uint4*)in,(uint4*)o,dinv,offs,srcs,st,st+C,g,be); break;
        default: break;
      }
    }
  };
  // mode 0+stats, mode 1 (relu), mode 3 (BN(old C) + add; st/g2/b2 = stats & params of that BN)
  auto gemm_m = [&](const u16* A, const u16* BT_, const float* bi, u16* Cc,
                    int K, int Nc, int mode, float* st, int sC,
                    const float* g2, const float* b2){
    dim3 g(cdiv(NN,128), Nc/128);
    if (mode == 0)
      k_mfma<0,true><<<g,256,0,stream>>>(A, BT_, bi, Cc, st, st + sC, nullptr, nullptr, NN, K, Nc);
    else if (mode == 1)
      k_mfma<1,false><<<g,256,0,stream>>>(A, BT_, bi, Cc, nullptr, nullptr, nullptr, nullptr, NN, K, Nc);
    else
      k_mfma<3,false><<<g,256,0,stream>>>(A, BT_, bi, Cc, st, st + sC, g2, b2, NN, K, Nc);
  };

  // stem
  agg(xb, ax, 128, nullptr, nullptr, nullptr);
  gemm_m(ax, wt0, b0, h0, 128, 256, 1, nullptr, 0, nullptr, nullptr);
  // block0 (256 -> 384 -> 512)
  agg(h0, ah0, 256, nullptr, nullptr, nullptr);
  gemm_m(ah0, wtA1, a_b1, t1, 256, 384, 0, sA1, 384, nullptr, nullptr);  // t1raw + stats
  agg(t1, at, 384, sA1, a_g1, a_be1);                                    // at = agg(relu(bn(t1raw)))
  gemm_m(at, wtA2, a_b2, h1, 384, 512, 0, sA2, 512, nullptr, nullptr);   // t2raw + stats
  gemm_m(ah0, wtA3, a_b3, h1, 256, 512, 3, sA2, 512, a_g2, a_be2);       // h1 = relu(bn(t2raw)) + ah0@w3+b3
  // block1 (512 -> 768 -> 1024)
  agg(h1, ah1, 512, nullptr, nullptr, nullptr);
  gemm_m(ah1, wtC1, c_b1, u1, 512, 768, 0, sC1, 768, nullptr, nullptr);  // u1raw + stats
  agg(u1, au, 768, sC1, c_g1, c_be1);                                    // au = agg(relu(bn(u1raw)))
  gemm_m(au, wtC2, c_b2, h2, 768, 1024, 0, sC2, 1024, nullptr, nullptr); // u2raw + stats
  gemm_m(ah1, wtC3, c_b3, h2, 512, 1024, 3, sC2, 1024, c_g2, c_be2);     // h2 = relu(bn(u2raw)) + ah1@c_w3+c_b3
  // pool (gather sorted rows) + MLP (fp32)
  k_pool_b<<<NG,256,0,stream>>>(h2, startg, rank, P);
  {
    dim3 g1(cdiv(NG,64), 1024/64);
    k_gemm<true><<<g1,256,0,stream>>>(P, mw1, mb1, Hh, NG, 1024, 1024);
    dim3 g2(cdiv(NG,64), 768/64);
    k_gemm<false><<<g2,256,0,stream>>>(Hh, mw2, mb2, out, NG, 1024, 768);
  }
}

// Round 14
// 673.507 us; speedup vs baseline: 1.2608x; 1.2608x over previous
//
#include <hip/hip_runtime.h>
#include <cstdint>
#include <cstddef>

#define NN 20000
#define NE 320000
#define NG 256
#define NB 79   // ceil(NN/256)

typedef unsigned short u16;
typedef __attribute__((ext_vector_type(8))) short bf16x8;
typedef __attribute__((ext_vector_type(4))) float f32x4;

// ---------------- bf16 helpers (storage bf16, math fp32) ----------------
__device__ inline float b2f(u16 h){
  union { unsigned u; float f; } v; v.u = ((unsigned)h) << 16; return v.f;
}
__device__ inline u16 f2b(float f){
  union { float f; unsigned u; } v; v.f = f;
  unsigned r = v.u + 0x7FFFu + ((v.u >> 16) & 1u);   // round-nearest-even
  return (u16)(r >> 16);
}
__device__ inline void up8(const uint4& v, float* a){
  union { unsigned u; float f; } t;
  t.u = v.x << 16;         a[0] = t.f;
  t.u = v.x & 0xffff0000u; a[1] = t.f;
  t.u = v.y << 16;         a[2] = t.f;
  t.u = v.y & 0xffff0000u; a[3] = t.f;
  t.u = v.z << 16;         a[4] = t.f;
  t.u = v.z & 0xffff0000u; a[5] = t.f;
  t.u = v.w << 16;         a[6] = t.f;
  t.u = v.w & 0xffff0000u; a[7] = t.f;
}
__device__ inline unsigned pk2(float a, float b){
  return (unsigned)f2b(a) | (((unsigned)f2b(b)) << 16);
}
__device__ inline void bnrelu8(float* b, const float* sc, const float* sh){
  #pragma unroll
  for (int k = 0; k < 8; k++) b[k] = fmaxf(fmaf(b[k], sc[k], sh[k]), 0.f);
}

__device__ inline void gload_lds16(const void* g, void* l){
  __builtin_amdgcn_global_load_lds(
      (const __attribute__((address_space(1))) unsigned int*)g,
      (__attribute__((address_space(3))) unsigned int*)l, 16, 0, 0);
}

// ---------------- utility kernels ----------------

__global__ void k_zero(int* __restrict__ p, int n){
  int i = blockIdx.x*blockDim.x + threadIdx.x;
  if (i < n) p[i] = 0;
}

__global__ void k_deg(const int* __restrict__ ei, int* __restrict__ deg){
  int e = blockIdx.x*blockDim.x + threadIdx.x;
  if (e < NE) atomicAdd(&deg[ei[NE + e]], 1);   // dst = ei[1][e]
}

// two-level scan: counts[NN] -> offs[NN+1]; also emits dinv
__global__ void k_scan1(const int* __restrict__ counts, int* __restrict__ bsum,
                        float* __restrict__ dinv){
  __shared__ int sm[256];
  int b = blockIdx.x, tid = threadIdx.x, idx = b*256 + tid;
  int v = (idx < NN) ? counts[idx] : 0;
  if (idx < NN) dinv[idx] = rsqrtf(1.0f + (float)v);
  sm[tid] = v;
  __syncthreads();
  for (int d = 128; d > 0; d >>= 1){
    if (tid < d) sm[tid] += sm[tid + d];
    __syncthreads();
  }
  if (tid == 0) bsum[b] = sm[0];
}
__global__ void k_scan2(int* __restrict__ bsum){
  if (threadIdx.x == 0){
    int c = 0;
    for (int i = 0; i < NB; i++){ int t = bsum[i]; bsum[i] = c; c += t; }
    bsum[NB] = c;
  }
}
__global__ void k_scan3(const int* __restrict__ counts, const int* __restrict__ bsum,
                        int* __restrict__ offs){
  __shared__ int sm[256];
  int b = blockIdx.x, tid = threadIdx.x, idx = b*256 + tid;
  int v = (idx < NN) ? counts[idx] : 0;
  sm[tid] = v;
  __syncthreads();
  for (int d = 1; d < 256; d <<= 1){
    int t = (tid >= d) ? sm[tid - d] : 0;
    __syncthreads();
    sm[tid] += t;
    __syncthreads();
  }
  if (idx < NN) offs[idx] = bsum[b] + sm[tid] - v;
  if (idx == NN - 1) offs[NN] = bsum[NB];
}

__global__ void k_fill(const int* __restrict__ ei, const int* __restrict__ offs,
                       int* __restrict__ cur, int* __restrict__ srcs){
  int e = blockIdx.x*blockDim.x + threadIdx.x;
  if (e < NE){
    int s = ei[e];
    int d = ei[NE + e];
    int p = atomicAdd(&cur[d], 1);
    srcs[offs[d] + p] = s;
  }
}

__global__ void k_bounds(const int* __restrict__ batch, int* __restrict__ start){
  int i = blockIdx.x*blockDim.x + threadIdx.x;
  if (i < NN){
    int b  = batch[i];
    int bp = (i == 0) ? -1 : batch[i-1];
    for (int g = bp + 1; g <= b; g++) start[g] = i;
    if (i == NN - 1){
      for (int g = b + 1; g <= NG; g++) start[g] = NN;
    }
  }
}

__global__ void k_cast(const float4* __restrict__ x, ushort4* __restrict__ xb, int total4){
  int t = blockIdx.x*blockDim.x + threadIdx.x;
  if (t >= total4) return;
  float4 v = x[t];
  ushort4 o; o.x = f2b(v.x); o.y = f2b(v.y); o.z = f2b(v.z); o.w = f2b(v.w);
  xb[t] = o;
}

// merged weight prep: 7 weights, fp32 [K,N] -> bf16 [N,K]
struct WPArgs {
  const float* w[7];
  u16* wt[7];
  int K[7], N[7];
  int tstart[8];   // tile prefix
};
__global__ __launch_bounds__(256) void k_wprep7(WPArgs a){
  __shared__ float sm[64][65];
  int bid = blockIdx.x;
  int wi = 0;
  while (wi < 6 && bid >= a.tstart[wi+1]) wi++;
  int tt = bid - a.tstart[wi];
  int K = a.K[wi], N = a.N[wi];
  int nk = K >> 6;
  int kb = (tt % nk) * 64, nb = (tt / nk) * 64;
  const float* w = a.w[wi];
  u16* wt = a.wt[wi];
  int tid = threadIdx.x;
  #pragma unroll
  for (int i = 0; i < 16; i++){
    int t = i*256 + tid;
    int r = t >> 6, c = t & 63;
    sm[r][c] = w[(size_t)(kb + r) * N + nb + c];
  }
  __syncthreads();
  #pragma unroll
  for (int i = 0; i < 16; i++){
    int t = i*256 + tid;
    int r = t >> 6, c = t & 63;
    wt[(size_t)(nb + r) * K + kb + c] = f2b(sm[c][r]);
  }
}

// ---------------- aggregation (bf16 in/out, fp32 accumulate) ----------------
// Linear layout (round-8 structure — empirical best). 4-edge unroll.
// T(x) = BN ? relu(sc*x+sh) : x with sc/sh derived inline from raw stats.
template<int C8, bool BN>
__global__ void k_agg_b(const uint4* __restrict__ in, uint4* __restrict__ out,
                        const float* __restrict__ dinv, const int* __restrict__ offs,
                        const int* __restrict__ srcs,
                        const float* __restrict__ sumv, const float* __restrict__ sqv,
                        const float* __restrict__ gam,  const float* __restrict__ bet){
  int t = blockIdx.x*blockDim.x + threadIdx.x;
  if (t >= NN * C8) return;
  int i = t / C8;
  int c = t - i * C8;
  float sc[8], sh[8];
  if (BN){
    #pragma unroll
    for (int k = 0; k < 8; k++){
      int ch = c*8 + k;
      float m  = sumv[ch] * (1.0f / NN);
      float vv = sqv[ch] * (1.0f / NN) - m * m;
      float rs = rsqrtf(vv + 1e-5f);
      sc[k] = gam[ch] * rs;
      sh[k] = bet[ch] - m * sc[k];
    }
  }
  float di = dinv[i];
  float a[8], acc[8];
  up8(in[t], a);
  if (BN) bnrelu8(a, sc, sh);
  #pragma unroll
  for (int k = 0; k < 8; k++) acc[k] = a[k] * di;

  int e = offs[i], e1 = offs[i + 1];
  for (; e + 4 <= e1; e += 4){
    int sA = srcs[e], sB = srcs[e+1], sC = srcs[e+2], sD = srcs[e+3];
    float dA = dinv[sA], dB = dinv[sB], dC = dinv[sC], dD = dinv[sD];
    uint4 yA = in[(size_t)sA * C8 + c];
    uint4 yB = in[(size_t)sB * C8 + c];
    uint4 yC = in[(size_t)sC * C8 + c];
    uint4 yD = in[(size_t)sD * C8 + c];
    float b[8];
    up8(yA, b);
    if (BN) bnrelu8(b, sc, sh);
    #pragma unroll
    for (int k = 0; k < 8; k++) acc[k] = fmaf(b[k], dA, acc[k]);
    up8(yB, b);
    if (BN) bnrelu8(b, sc, sh);
    #pragma unroll
    for (int k = 0; k < 8; k++) acc[k] = fmaf(b[k], dB, acc[k]);
    up8(yC, b);
    if (BN) bnrelu8(b, sc, sh);
    #pragma unroll
    for (int k = 0; k < 8; k++) acc[k] = fmaf(b[k], dC, acc[k]);
    up8(yD, b);
    if (BN) bnrelu8(b, sc, sh);
    #pragma unroll
    for (int k = 0; k < 8; k++) acc[k] = fmaf(b[k], dD, acc[k]);
  }
  for (; e < e1; e++){
    int s = srcs[e];
    float ds = dinv[s];
    float b[8];
    up8(in[(size_t)s * C8 + c], b);
    if (BN) bnrelu8(b, sc, sh);
    #pragma unroll
    for (int k = 0; k < 8; k++) acc[k] = fmaf(b[k], ds, acc[k]);
  }
  #pragma unroll
  for (int k = 0; k < 8; k++) acc[k] *= di;
  uint4 o;
  o.x = pk2(acc[0], acc[1]); o.y = pk2(acc[2], acc[3]);
  o.z = pk2(acc[4], acc[5]); o.w = pk2(acc[6], acc[7]);
  out[t] = o;
}

// ---------------- MFMA GEMM: A bf16 [M,K], BT bf16 [N,K], C bf16 [M,N] ----------------
// MODE: 0=bias, 1=bias+relu, 3=bias + relu(BN(C_old)) add (BN from raw stats p0..p3)
// STATS: accumulate per-column sum/sumsq of (acc+bias) into p0/p1
template<int MODE, bool STATS>
__global__ __launch_bounds__(256, 4) void k_mfma(const u16* __restrict__ A,
                                                 const u16* __restrict__ BT,
                                                 const float* __restrict__ bias,
                                                 u16* __restrict__ C,
                                                 float* __restrict__ p0,
                                                 float* __restrict__ p1,
                                                 const float* __restrict__ p2,
                                                 const float* __restrict__ p3,
                                                 int M, int K, int Nc){
  __shared__ u16 S[128*128];          // staging: As = S[0:8192), Bs = S[8192:16384)
  u16* As = S;
  u16* Bs = S + 128*64;
  const int tid = threadIdx.x;
  const int lane = tid & 63;
  const int quad = lane >> 4;
  const int l16 = lane & 15;
  const int wid = tid >> 6;
  const int wm = wid & 1, wn = wid >> 1;
  const int bm = blockIdx.x * 128, bn = blockIdx.y * 128;

  f32x4 acc[4][4];
  #pragma unroll
  for (int i = 0; i < 4; i++)
    #pragma unroll
    for (int j = 0; j < 4; j++)
      acc[i][j] = (f32x4){0.f, 0.f, 0.f, 0.f};

  const int srow = tid >> 3;
  const int scol8 = tid & 7;
  for (int k0 = 0; k0 < K; k0 += 64){
    #pragma unroll
    for (int i = 0; i < 4; i++){
      int row = i*32 + srow;
      int gc = (scol8 ^ (row & 7)) * 8;
      int lofs = row*64 + scol8*8;
      gload_lds16(A + (size_t)(bm + row) * K + k0 + gc, As + lofs);
      gload_lds16(BT + (size_t)(bn + row) * K + k0 + gc, Bs + lofs);
    }
    __syncthreads();
    #pragma unroll
    for (int kk = 0; kk < 2; kk++){
      const int col8 = kk*4 + quad;
      bf16x8 af[4], bfr[4];
      #pragma unroll
      for (int mi = 0; mi < 4; mi++){
        int row = wm*64 + mi*16 + l16;
        af[mi] = *(const bf16x8*)(As + row*64 + ((col8 ^ (row & 7)) * 8));
      }
      #pragma unroll
      for (int ni = 0; ni < 4; ni++){
        int row = wn*64 + ni*16 + l16;
        bfr[ni] = *(const bf16x8*)(Bs + row*64 + ((col8 ^ (row & 7)) * 8));
      }
      #pragma unroll
      for (int mi = 0; mi < 4; mi++)
        #pragma unroll
        for (int ni = 0; ni < 4; ni++)
          acc[mi][ni] = __builtin_amdgcn_mfma_f32_16x16x32_bf16(af[mi], bfr[ni], acc[mi][ni], 0, 0, 0);
    }
    __syncthreads();
  }
  // register epilogue: bias (+stats, +relu), round to bf16 into LDS [row][col]
  #pragma unroll
  for (int ni = 0; ni < 4; ni++){
    int colL = wn*64 + ni*16 + l16;
    float bb = bias[bn + colL];
    float s = 0.f, s2 = 0.f;
    #pragma unroll
    for (int mi = 0; mi < 4; mi++){
      int rbase = wm*64 + mi*16 + quad*4;
      #pragma unroll
      for (int r = 0; r < 4; r++){
        int rowL = rbase + r;
        float v = acc[mi][ni][r] + bb;
        if (STATS && (bm + rowL) < M){ s += v; s2 += v * v; }
        if (MODE == 1) v = fmaxf(v, 0.f);
        S[rowL*128 + colL] = f2b(v);
      }
    }
    if (STATS){
      s  += __shfl_xor(s, 16, 64);  s  += __shfl_xor(s, 32, 64);
      s2 += __shfl_xor(s2, 16, 64); s2 += __shfl_xor(s2, 32, 64);
      if (quad == 0){
        atomicAdd(&p0[bn + colL], s);
        atomicAdd(&p1[bn + colL], s2);
      }
    }
  }
  __syncthreads();
  // blast: 16B per lane, full-line coalesced stores
  #pragma unroll
  for (int it = 0; it < 8; it++){
    int idx = it*256 + tid;
    int rl = idx >> 4, cq = idx & 15;
    int row = bm + rl;
    if (row < M){
      int col0 = bn + cq*8;
      uint4 w = *(const uint4*)(S + rl*128 + cq*8);
      u16* cp = C + (size_t)row * Nc + col0;
      if (MODE == 3){
        float o[8], ov[8];
        up8(w, o);
        uint4 old = *(const uint4*)cp;
        up8(old, ov);
        #pragma unroll
        for (int k = 0; k < 8; k++){
          int ch = col0 + k;
          float m  = p0[ch] * (1.0f / NN);
          float vv = p1[ch] * (1.0f / NN) - m * m;
          float rs = rsqrtf(vv + 1e-5f);
          float sc = p2[ch] * rs;
          float sh = p3[ch] - m * sc;
          o[k] += fmaxf(fmaf(ov[k], sc, sh), 0.f);
        }
        uint4 ou;
        ou.x = pk2(o[0], o[1]); ou.y = pk2(o[2], o[3]);
        ou.z = pk2(o[4], o[5]); ou.w = pk2(o[6], o[7]);
        *(uint4*)cp = ou;
      } else {
        *(uint4*)cp = w;
      }
    }
  }
}

// ---------------- fp32 split-K GEMM (MLP tail, M=256) ----------------
// grid (M/64, Nc/64, SPLITS); each block accumulates its K-chunk into zeroed C
// via fp32 atomics; bias added by split z==0. RELUA applies relu to A on load.
template<bool RELUA>
__global__ __launch_bounds__(256) void k_gemm_sk(const float* __restrict__ A,
                                                 const float* __restrict__ B,
                                                 const float* __restrict__ bias,
                                                 float* __restrict__ C,
                                                 int M, int K, int Nc){
  __shared__ float As[16][68];
  __shared__ float Bs[16][64];
  const int tid = threadIdx.x;
  const int tx = tid & 15, ty = tid >> 4;
  const int bm = blockIdx.x * 64, bn = blockIdx.y * 64;
  const int kchunk = K / gridDim.z;
  const int ks = blockIdx.z * kchunk, ke = ks + kchunk;
  const int arow = tid >> 2, akq = (tid & 3) << 2;
  const int brow = tid >> 4, bcol = (tid & 15) << 2;
  float acc[4][4] = {{0.f}};
  const bool aval = (bm + arow) < M;
  const float* Aptr = A + (size_t)(bm + arow) * K + akq;
  const float* Bptr = B + (size_t)brow * Nc + bn + bcol;
  for (int k0 = ks; k0 < ke; k0 += 16){
    float4 av = make_float4(0.f, 0.f, 0.f, 0.f);
    if (aval) av = *(const float4*)(Aptr + k0);
    if (RELUA){
      av.x = fmaxf(av.x, 0.f); av.y = fmaxf(av.y, 0.f);
      av.z = fmaxf(av.z, 0.f); av.w = fmaxf(av.w, 0.f);
    }
    float4 bv = *(const float4*)(Bptr + (size_t)k0 * Nc);
    As[akq + 0][arow] = av.x;
    As[akq + 1][arow] = av.y;
    As[akq + 2][arow] = av.z;
    As[akq + 3][arow] = av.w;
    *(float4*)&Bs[brow][bcol] = bv;
    __syncthreads();
    #pragma unroll
    for (int kk = 0; kk < 16; kk++){
      const float4 a = *(const float4*)(&As[kk][ty << 2]);
      const float4 b = *(const float4*)(&Bs[kk][tx << 2]);
      const float ar[4] = {a.x, a.y, a.z, a.w};
      const float br[4] = {b.x, b.y, b.z, b.w};
      #pragma unroll
      for (int i = 0; i < 4; i++)
        #pragma unroll
        for (int j = 0; j < 4; j++)
          acc[i][j] = fmaf(ar[i], br[j], acc[i][j]);
    }
    __syncthreads();
  }
  const int col = bn + (tx << 2);
  float4 bb = make_float4(0.f, 0.f, 0.f, 0.f);
  if (blockIdx.z == 0) bb = *(const float4*)(bias + col);
  #pragma unroll
  for (int i = 0; i < 4; i++){
    int row = bm + (ty << 2) + i;
    if (row < M){
      float* cp = C + (size_t)row * Nc + col;
      atomicAdd(cp + 0, acc[i][0] + bb.x);
      atomicAdd(cp + 1, acc[i][1] + bb.y);
      atomicAdd(cp + 2, acc[i][2] + bb.z);
      atomicAdd(cp + 3, acc[i][3] + bb.w);
    }
  }
}

// ---------------- mean pool: h2 bf16 [NN,1024] -> pooled fp32 [NG,1024] ----------------
__global__ __launch_bounds__(256) void k_pool_b(const u16* __restrict__ h,
                                                const int* __restrict__ start,
                                                float* __restrict__ pooled){
  __shared__ float sm[128*8];
  int g = blockIdx.x;
  int half = threadIdx.x >> 7;
  int cb = threadIdx.x & 127;
  int c = cb << 3;
  int r0 = start[g], r1 = start[g + 1];
  float acc[8] = {0.f,0.f,0.f,0.f,0.f,0.f,0.f,0.f};
  for (int r = r0 + half; r < r1; r += 2){
    float b[8];
    up8(*(const uint4*)(h + (size_t)r * 1024 + c), b);
    #pragma unroll
    for (int k = 0; k < 8; k++) acc[k] += b[k];
  }
  if (half){
    #pragma unroll
    for (int k = 0; k < 8; k++) sm[cb*8 + k] = acc[k];
  }
  __syncthreads();
  if (!half){
    float inv = (r1 > r0) ? (1.0f / (float)(r1 - r0)) : 0.0f;
    float o[8];
    #pragma unroll
    for (int k = 0; k < 8; k++) o[k] = (acc[k] + sm[cb*8 + k]) * inv;
    float4* dst = (float4*)(pooled + (size_t)g * 1024 + c);
    dst[0] = make_float4(o[0], o[1], o[2], o[3]);
    dst[1] = make_float4(o[4], o[5], o[6], o[7]);
  }
}

// ---------------- host launcher ----------------

extern "C" void kernel_launch(void* const* d_in, const int* in_sizes, int n_in,
                              void* d_out, int out_size, void* d_ws, size_t ws_size,
                              hipStream_t stream) {
  const float* x    = (const float*)d_in[0];
  const int*   ei   = (const int*)d_in[1];
  const int*   bat  = (const int*)d_in[2];
  const float* w0   = (const float*)d_in[3];
  const float* b0   = (const float*)d_in[4];
  const float* a_w1 = (const float*)d_in[5],  *a_b1  = (const float*)d_in[6];
  const float* a_g1 = (const float*)d_in[7],  *a_be1 = (const float*)d_in[8];
  const float* a_w2 = (const float*)d_in[9],  *a_b2  = (const float*)d_in[10];
  const float* a_g2 = (const float*)d_in[11], *a_be2 = (const float*)d_in[12];
  const float* a_w3 = (const float*)d_in[13], *a_b3  = (const float*)d_in[14];
  const float* c_w1 = (const float*)d_in[15], *c_b1  = (const float*)d_in[16];
  const float* c_g1 = (const float*)d_in[17], *c_be1 = (const float*)d_in[18];
  const float* c_w2 = (const float*)d_in[19], *c_b2  = (const float*)d_in[20];
  const float* c_g2 = (const float*)d_in[21], *c_be2 = (const float*)d_in[22];
  const float* c_w3 = (const float*)d_in[23], *c_b3  = (const float*)d_in[24];
  const float* mw1  = (const float*)d_in[25], *mb1   = (const float*)d_in[26];
  const float* mw2  = (const float*)d_in[27], *mb2   = (const float*)d_in[28];
  float* out = (float*)d_out;

  char* pp = (char*)d_ws;
  auto alloc = [&](size_t b)->char*{ char* r = pp; pp += (b + 255) & ~(size_t)255; return r; };

  const size_t CH = (size_t)NN * 2;
  char* R = alloc(2304 * CH);                      // 92.16 MB
  float* dinv = (float*)alloc((size_t)NN * 4);
  int* icomb  = (int*)alloc((size_t)2 * NN * 4);   // deg + cur
  int* deg    = icomb;
  int* cur    = icomb + NN;
  int* offs   = (int*)alloc((size_t)(NN + 1) * 4);
  int* bsum   = (int*)alloc((size_t)(NB + 1) * 4);
  int* srcs   = (int*)alloc((size_t)NE * 4);
  int* startg = (int*)alloc((size_t)(NG + 1) * 4);
  float* SB   = (float*)alloc(5376 * 4);
  float* sA1 = SB;          // 384*2
  float* sA2 = SB + 768;    // 512*2
  float* sC1 = SB + 1792;   // 768*2
  float* sC2 = SB + 3328;   // 1024*2
  u16* WT  = (u16*)alloc(2162688 * 2);             // 4.33 MB
  u16* wt0  = WT;                // 256x128
  u16* wtA1 = WT + 32768;        // 384x256
  u16* wtA2 = WT + 131072;       // 512x384
  u16* wtA3 = WT + 327680;       // 512x256
  u16* wtC1 = WT + 458752;       // 768x512
  u16* wtC2 = WT + 851968;       // 1024x768
  u16* wtC3 = WT + 1638400;      // 1024x512
  float* P  = (float*)WT;        // overlaid with WT (disjoint lifetime)
  float* Hh = P + (size_t)NG * 1024;

  auto slot = [&](int s)->u16*{ return (u16*)(R + (size_t)s * CH); };
  u16* xb  = slot(512);
  u16* ax  = slot(0);
  u16* h0  = slot(128);
  u16* ah0 = slot(1664);
  u16* t1  = slot(1920);
  u16* at  = slot(1280);
  u16* h1  = slot(768);
  u16* ah1 = slot(1792);
  u16* u1  = slot(0);
  u16* au  = slot(1024);
  u16* h2  = slot(0);

  auto cdiv = [](int a, int b){ return (a + b - 1) / b; };

  // graph preprocessing
  k_zero<<<cdiv(2*NN,256),256,0,stream>>>(icomb, 2*NN);
  k_zero<<<cdiv(5376,256),256,0,stream>>>((int*)SB, 5376);
  k_deg <<<cdiv(NE,256),256,0,stream>>>(ei, deg);
  k_scan1<<<NB,256,0,stream>>>(deg, bsum, dinv);
  k_scan2<<<1,64,0,stream>>>(bsum);
  k_scan3<<<NB,256,0,stream>>>(deg, bsum, offs);
  k_fill<<<cdiv(NE,256),256,0,stream>>>(ei, offs, cur, srcs);
  k_bounds<<<cdiv(NN,256),256,0,stream>>>(bat, startg);
  k_cast<<<cdiv(NN*32,256),256,0,stream>>>((const float4*)x, (ushort4*)xb, NN*32);

  // merged weight prep (fp32 [K,N] -> bf16 [N,K], 7 weights, 1 launch)
  {
    WPArgs wa;
    const float* ws[7] = {w0, a_w1, a_w2, a_w3, c_w1, c_w2, c_w3};
    u16* wts[7] = {wt0, wtA1, wtA2, wtA3, wtC1, wtC2, wtC3};
    int Ks[7] = {128, 256, 384, 256, 512, 768, 512};
    int Ns[7] = {256, 384, 512, 512, 768, 1024, 1024};
    int acc = 0;
    for (int i = 0; i < 7; i++){
      wa.w[i] = ws[i]; wa.wt[i] = wts[i]; wa.K[i] = Ks[i]; wa.N[i] = Ns[i];
      wa.tstart[i] = acc;
      acc += (Ks[i]/64) * (Ns[i]/64);
    }
    wa.tstart[7] = acc;
    k_wprep7<<<acc,256,0,stream>>>(wa);
  }

  // agg: linear; plain or fused BN-apply of input from raw stats
  auto agg = [&](const u16* in, u16* o, int C, const float* st,
                 const float* g, const float* be){
    int C8 = C / 8;
    int gb = cdiv(NN * C8, 256);
    if (!st){
      switch (C8){
        case 16: k_agg_b<16,false><<<gb,256,0,stream>>>((const uint4*)in,(uint4*)o,dinv,offs,srcs,nullptr,nullptr,nullptr,nullptr); break;
        case 32: k_agg_b<32,false><<<gb,256,0,stream>>>((const uint4*)in,(uint4*)o,dinv,offs,srcs,nullptr,nullptr,nullptr,nullptr); break;
        case 64: k_agg_b<64,false><<<gb,256,0,stream>>>((const uint4*)in,(uint4*)o,dinv,offs,srcs,nullptr,nullptr,nullptr,nullptr); break;
        default: break;
      }
    } else {
      switch (C8){
        case 48: k_agg_b<48,true><<<gb,256,0,stream>>>((const uint4*)in,(uint4*)o,dinv,offs,srcs,st,st+C,g,be); break;
        case 96: k_agg_b<96,true><<<gb,256,0,stream>>>((const uint4*)in,(uint4*)o,dinv,offs,srcs,st,st+C,g,be); break;
        default: break;
      }
    }
  };
  // mode 0+stats, mode 1 (relu), mode 3 (BN(old C) + add)
  auto gemm_m = [&](const u16* A, const u16* BT_, const float* bi, u16* Cc,
                    int K, int Nc, int mode, float* st, int sC,
                    const float* g2, const float* b2){
    dim3 g(cdiv(NN,128), Nc/128);
    if (mode == 0)
      k_mfma<0,true><<<g,256,0,stream>>>(A, BT_, bi, Cc, st, st + sC, nullptr, nullptr, NN, K, Nc);
    else if (mode == 1)
      k_mfma<1,false><<<g,256,0,stream>>>(A, BT_, bi, Cc, nullptr, nullptr, nullptr, nullptr, NN, K, Nc);
    else
      k_mfma<3,false><<<g,256,0,stream>>>(A, BT_, bi, Cc, st, st + sC, g2, b2, NN, K, Nc);
  };

  // stem
  agg(xb, ax, 128, nullptr, nullptr, nullptr);
  gemm_m(ax, wt0, b0, h0, 128, 256, 1, nullptr, 0, nullptr, nullptr);
  // block0 (256 -> 384 -> 512)
  agg(h0, ah0, 256, nullptr, nullptr, nullptr);
  gemm_m(ah0, wtA1, a_b1, t1, 256, 384, 0, sA1, 384, nullptr, nullptr);  // t1raw + stats
  agg(t1, at, 384, sA1, a_g1, a_be1);                                    // at = agg(relu(bn(t1raw)))
  gemm_m(at, wtA2, a_b2, h1, 384, 512, 0, sA2, 512, nullptr, nullptr);   // t2raw + stats
  gemm_m(ah0, wtA3, a_b3, h1, 256, 512, 3, sA2, 512, a_g2, a_be2);       // h1 = relu(bn(t2raw)) + ah0@w3+b3
  // block1 (512 -> 768 -> 1024)
  agg(h1, ah1, 512, nullptr, nullptr, nullptr);
  gemm_m(ah1, wtC1, c_b1, u1, 512, 768, 0, sC1, 768, nullptr, nullptr);  // u1raw + stats
  agg(u1, au, 768, sC1, c_g1, c_be1);                                    // au = agg(relu(bn(u1raw)))
  gemm_m(au, wtC2, c_b2, h2, 768, 1024, 0, sC2, 1024, nullptr, nullptr); // u2raw + stats
  gemm_m(ah1, wtC3, c_b3, h2, 512, 1024, 3, sC2, 1024, c_g2, c_be2);     // h2 = relu(bn(u2raw)) + ah1@c_w3+c_b3
  // pool + MLP (fp32, split-K for latency)
  k_pool_b<<<NG,256,0,stream>>>(h2, startg, P);
  {
    k_zero<<<cdiv(NG*1024,256),256,0,stream>>>((int*)Hh, NG*1024);
    k_zero<<<cdiv(NG*768,256),256,0,stream>>>((int*)out, NG*768);
    dim3 g1(cdiv(NG,64), 1024/64, 8);
    k_gemm_sk<false><<<g1,256,0,stream>>>(P, mw1, mb1, Hh, NG, 1024, 1024);
    dim3 g2(cdiv(NG,64), 768/64, 8);
    k_gemm_sk<true><<<g2,256,0,stream>>>(Hh, mw2, mb2, out, NG, 1024, 768);
  }
}